// Round 1
// baseline (1058.662 us; speedup 1.0000x reference)
//
#include <hip/hip_runtime.h>
#include <math.h>

// Block-circulant SwiGLU FFN via per-wave FFT-512 (CirCNN style).
// d_model=2048 (p=4 blocks), d_ff=5632 (q=11 blocks), BLOCK=512.

#define WAVE_FENCE() do { asm volatile("s_waitcnt lgkmcnt(0)" ::: "memory"); \
                          __builtin_amdgcn_sched_barrier(0); } while (0)

// In-place Stockham radix-2 complex FFT, N=512, executed by one 64-lane wave.
// rr/ii: wave-private LDS buffers [512]. Wt: LDS table Wt[j] = (cos, -sin)(2*pi*j/512)
// i.e. the FORWARD twiddle e^{-i theta}. INV=true conjugates (inverse, unscaled).
// Per stage: register-stage all reads, lgkmcnt(0) fence, then writes -> in-place safe.
template<bool INV>
__device__ __forceinline__ void fft512_ip(float* rr, float* ii, const float2* Wt, int t)
{
#pragma unroll
    for (int st = 0; st < 9; ++st) {
        const int s = 1 << st;
        float ar[4], ai[4], br[4], bi[4];
#pragma unroll
        for (int u = 0; u < 4; ++u) {
            const int bf = t + 64 * u;           // butterfly id 0..255
            ar[u] = rr[bf];        ai[u] = ii[bf];
            br[u] = rr[bf + 256];  bi[u] = ii[bf + 256];
        }
        WAVE_FENCE();   // all reads physically complete before any write issues
#pragma unroll
        for (int u = 0; u < 4; ++u) {
            const int bf = t + 64 * u;
            const int qq = bf & (s - 1);
            const int j  = bf ^ qq;              // twiddle index = p * (512/n)
            const float2 wv = Wt[j];
            const float wr = wv.x;
            const float wi = INV ? -wv.y : wv.y;
            const float sr_ = ar[u] + br[u], si_ = ai[u] + bi[u];
            const float dr  = ar[u] - br[u], di  = ai[u] - bi[u];
            const int wa = 2 * bf - qq;
            rr[wa]     = sr_;
            ii[wa]     = si_;
            rr[wa + s] = dr * wr - di * wi;
            ii[wa + s] = dr * wi + di * wr;
        }
        WAVE_FENCE();   // stage writes visible before next stage reads
    }
}

// ---------------- weight spectra precompute: one wave per weight block ----------------
// ws layout (float2): Wgf[44*257] | Wuf[44*257] | Wdf[44*257], each entry rfft(w)/512.
__global__ __launch_bounds__(64) void wf_prep(const float* __restrict__ wg,
                                              const float* __restrict__ wu,
                                              const float* __restrict__ wd,
                                              float2* __restrict__ wsp)
{
    __shared__ float2 sW[256];
    __shared__ float  s_r[512];
    __shared__ float  s_i[512];
    const int t = threadIdx.x;

#pragma unroll
    for (int i = 0; i < 4; ++i) {
        const int j = t + 64 * i;
        const float th = 6.283185307179586f * (float)j * (1.0f / 512.0f);
        sW[j] = make_float2(cosf(th), -sinf(th));
    }

    const int wid = blockIdx.x;       // 0..131
    const float* src;
    float2* dst;
    if (wid < 44)      { src = wg + (size_t)wid * 512;        dst = wsp + (size_t)wid * 257; }
    else if (wid < 88) { src = wu + (size_t)(wid - 44) * 512; dst = wsp + (size_t)44 * 257 + (size_t)(wid - 44) * 257; }
    else               { src = wd + (size_t)(wid - 88) * 512; dst = wsp + (size_t)88 * 257 + (size_t)(wid - 88) * 257; }

#pragma unroll
    for (int u = 0; u < 8; ++u) { const int n = t + 64 * u; s_r[n] = src[n]; s_i[n] = 0.0f; }
    WAVE_FENCE();
    fft512_ip<false>(s_r, s_i, sW, t);
    const float sc = 1.0f / 512.0f;   // fold irfft 1/N into the weight spectrum
#pragma unroll
    for (int u = 0; u < 5; ++u) {
        const int k = t + 64 * u;
        if (k <= 256) dst[k] = make_float2(s_r[k] * sc, s_i[k] * sc);
    }
}

// ---------------- main fused FFN kernel: one 256-thread block per row ----------------
__global__ __launch_bounds__(256) void bcffn(const float* __restrict__ x,
                                             const float2* __restrict__ wsp,
                                             float* __restrict__ out)
{
    __shared__ float2 sW[256];        //  2 KB twiddles
    __shared__ float  s_r[4][512];    //  8 KB per-wave FFT buffers (re)
    __shared__ float  s_i[4][512];    //  8 KB (im)
    __shared__ float2 sXf[4][257];    //  8.2 KB  X spectra (half, Hermitian)
    __shared__ float2 sHf[11][257];   // 22.6 KB  H spectra (half)
                                      // total ~49.2 KB -> 3 blocks/CU

    const int tid = threadIdx.x;
    const int t   = tid & 63;
    const int w   = tid >> 6;         // wave id 0..3
    const size_t row = blockIdx.x;

    {
        const float th = 6.283185307179586f * (float)tid * (1.0f / 512.0f);
        sW[tid] = make_float2(cosf(th), -sinf(th));
    }
    __syncthreads();

    const float2* Wg = wsp;
    const float2* Wu = wsp + 44 * 257;
    const float2* Wd = wsp + 88 * 257;

    float* rr = s_r[w];
    float* ii = s_i[w];

    // ---- Phase 1: wave w computes Xf[p=w] = FFT(x block w) ----
    const float* xrow = x + row * 2048 + (size_t)w * 512;
#pragma unroll
    for (int u = 0; u < 8; ++u) { const int n = t + 64 * u; rr[n] = xrow[n]; ii[n] = 0.0f; }
    WAVE_FENCE();
    fft512_ip<false>(rr, ii, sW, t);
#pragma unroll
    for (int u = 0; u < 5; ++u) {
        const int k = t + 64 * u;
        if (k <= 256) sXf[w][k] = make_float2(rr[k], ii[k]);
    }
    __syncthreads();

    // ---- Phase 2: q-loop. G = Xf*Wg, U = Xf*Wu; z = iFFT(G + i*U) -> g=Re, u=Im;
    //      h = silu(g)*u; Hf[q] = FFT(h). One inverse FFT serves both g and u. ----
#pragma unroll 1
    for (int r = 0; r < 3; ++r) {
        const int q = r * 4 + w;
        if (q < 11) {
#pragma unroll
            for (int u = 0; u < 5; ++u) {
                const int k = t + 64 * u;
                if (k <= 256) {
                    float gr = 0.f, gi = 0.f, ur = 0.f, ui = 0.f;
#pragma unroll
                    for (int p = 0; p < 4; ++p) {
                        const float2 X = sXf[p][k];
                        const float2 a = Wg[(q * 4 + p) * 257 + k];
                        const float2 b = Wu[(q * 4 + p) * 257 + k];
                        gr += X.x * a.x - X.y * a.y;  gi += X.x * a.y + X.y * a.x;
                        ur += X.x * b.x - X.y * b.y;  ui += X.x * b.y + X.y * b.x;
                    }
                    // packed spectrum Z = G + i*U (both Hermitian -> z = g + i*u real/imag)
                    rr[k] = gr - ui;  ii[k] = gi + ur;
                    if (k >= 1 && k <= 255) {       // mirror: Z[512-k] = conj(G)+i*conj(U)
                        rr[512 - k] = gr + ui;
                        ii[512 - k] = ur - gi;
                    }
                }
            }
            WAVE_FENCE();
            fft512_ip<true>(rr, ii, sW, t);         // unscaled inverse; 1/512 lives in W
#pragma unroll
            for (int u = 0; u < 8; ++u) {
                const int n = t + 64 * u;
                const float g  = rr[n];
                const float uu = ii[n];
                const float h  = g * uu / (1.0f + __expf(-g));   // silu(g)*u
                rr[n] = h;  ii[n] = 0.0f;
            }
            WAVE_FENCE();
            fft512_ip<false>(rr, ii, sW, t);
#pragma unroll
            for (int u = 0; u < 5; ++u) {
                const int k = t + 64 * u;
                if (k <= 256) sHf[q][k] = make_float2(rr[k], ii[k]);
            }
            WAVE_FENCE();   // Hf-store reads drained before next round's einsum writes
        }
    }
    __syncthreads();

    // ---- Phase 3: wave w = output block pp. Z = sum_q Hf[q]*Wd[pp,q]; out = iFFT(Z) ----
#pragma unroll
    for (int u = 0; u < 5; ++u) {
        const int k = t + 64 * u;
        if (k <= 256) {
            float zr = 0.f, zi = 0.f;
#pragma unroll
            for (int q = 0; q < 11; ++q) {
                const float2 H = sHf[q][k];
                const float2 d = Wd[(w * 11 + q) * 257 + k];
                zr += H.x * d.x - H.y * d.y;
                zi += H.x * d.y + H.y * d.x;
            }
            rr[k] = zr;  ii[k] = zi;
            if (k >= 1 && k <= 255) { rr[512 - k] = zr; ii[512 - k] = -zi; }
        }
    }
    WAVE_FENCE();
    fft512_ip<true>(rr, ii, sW, t);
    float* orow = out + row * 2048 + (size_t)w * 512;
#pragma unroll
    for (int u = 0; u < 8; ++u) { const int n = t + 64 * u; orow[n] = rr[n]; }
}

extern "C" void kernel_launch(void* const* d_in, const int* in_sizes, int n_in,
                              void* d_out, int out_size, void* d_ws, size_t ws_size,
                              hipStream_t stream)
{
    (void)n_in; (void)out_size; (void)ws_size;
    const float* x  = (const float*)d_in[0];
    const float* wg = (const float*)d_in[1];
    const float* wu = (const float*)d_in[2];
    const float* wd = (const float*)d_in[3];
    float2* wsp = (float2*)d_ws;          // 132*257 float2 = 271 KB used
    float*  out = (float*)d_out;

    const int rows = in_sizes[0] / 2048;  // 16384

    wf_prep<<<132, 64, 0, stream>>>(wg, wu, wd, wsp);
    bcffn<<<rows, 256, 0, stream>>>(x, wsp, out);
}